// Round 15
// baseline (200.201 us; speedup 1.0000x reference)
//
#include <hip/hip_runtime.h>

#define SEQ     2048
#define DMODEL  1024
#define NHEADS  16
#define DKH     64
#define BATCH   4

typedef __bf16 bf16x8 __attribute__((ext_vector_type(8)));
typedef float  f32x4  __attribute__((ext_vector_type(4)));

static __device__ __forceinline__ unsigned short f2bf(float x) {
  unsigned int u = __float_as_uint(x);
  u += 0x7fffu + ((u >> 16) & 1u);
  return (unsigned short)(u >> 16);
}
static __device__ __forceinline__ float bf2f(unsigned short b) {
  return __uint_as_float(((unsigned int)b) << 16);
}
static __device__ __forceinline__ void gload_lds16(const void* g, void* lds) {
  __builtin_amdgcn_global_load_lds((const __attribute__((address_space(1))) void*)g,
                                   (__attribute__((address_space(3))) void*)lds,
                                   16, 0, 0);
}
static __device__ __forceinline__ f32x4 mfma16(bf16x8 a, bf16x8 b, f32x4 c) {
  return __builtin_amdgcn_mfma_f32_16x16x32_bf16(a, b, c, 0, 0, 0);
}

// ---------------- fp32 -> bf16 cast ----------------
__global__ void cast_kernel(const float* __restrict__ src,
                            unsigned short* __restrict__ dst, int n4) {
  int i = blockIdx.x * 256 + threadIdx.x;
  if (i >= n4) return;
  float4 v = ((const float4*)src)[i];
  ushort4 o;
  o.x = f2bf(v.x); o.y = f2bf(v.y); o.z = f2bf(v.z); o.w = f2bf(v.w);
  ((ushort4*)dst)[i] = o;
}

// 4 weight matrices in one launch (blockIdx.y selects)
__global__ void cast4_kernel(const float* __restrict__ s0, const float* __restrict__ s1,
                             const float* __restrict__ s2, const float* __restrict__ s3,
                             unsigned short* __restrict__ d0, unsigned short* __restrict__ d1,
                             unsigned short* __restrict__ d2, unsigned short* __restrict__ d3,
                             int n4) {
  int i = blockIdx.x * 256 + threadIdx.x;
  if (i >= n4) return;
  const float* s = (blockIdx.y == 0) ? s0 : (blockIdx.y == 1) ? s1 : (blockIdx.y == 2) ? s2 : s3;
  unsigned short* d = (blockIdx.y == 0) ? d0 : (blockIdx.y == 1) ? d1 : (blockIdx.y == 2) ? d2 : d3;
  float4 v = ((const float4*)s)[i];
  ushort4 o;
  o.x = f2bf(v.x); o.y = f2bf(v.y); o.z = f2bf(v.z); o.w = f2bf(v.w);
  ((ushort4*)d)[i] = o;
}

// ---------------- GEMM: C = A (8192x1024) * W^T, W is [out][in] ----------------
// 128x128 tile, 4 waves, BK=32, THREE LDS buffers (48 KiB -> 3 blocks/CU,
// 12 waves/CU at VGPR<=168), ONE barrier per K-tile:
//   vmcnt(4) [tile t landed; t+1 flying] -> s_barrier -> STAGE(t+2) into
//   buf[(t-1)%3] (reads finished in iter t-1, all waves past this barrier)
//   -> 8 ds_read_b128 -> 16 MFMA.
// EPI 0: RoPE fused into Q/K epilogue (Q scaled by log2e/8); V (z==2) -> V^T.
// EPI 1: fp32 [m][1024].
template<int EPI>
__global__ __launch_bounds__(256, 3)
void gemm_bt(const unsigned short* __restrict__ A,
             const unsigned short* __restrict__ W0,
             const unsigned short* __restrict__ W1,
             const unsigned short* __restrict__ W2,
             unsigned short* __restrict__ O0,
             unsigned short* __restrict__ O1,
             unsigned short* __restrict__ O2,
             float* __restrict__ Of)
{
  __shared__ unsigned short sA[3][128*32];   // 3 x 8 KiB
  __shared__ unsigned short sB[3][128*32];   // 3 x 8 KiB  (48 KiB total)
  const int tid = threadIdx.x;
  const int lane = tid & 63, w = tid >> 6;
  const int wm = w >> 1, wn = w & 1;
  const int li = lane & 15, lg = lane >> 4;

  const int NWG = (EPI == 0) ? 1536 : 512;
  const int CPX = NWG / 8;
  const int lgid = (blockIdx.x & 7) * CPX + (blockIdx.x >> 3);
  const int n0 = (lgid & 7) * 128;
  const int m0 = ((lgid >> 3) & 63) * 128;
  const int z  = (EPI == 0) ? (lgid >> 9) : 0;
  const unsigned short* Bw = (EPI == 0)
      ? ((z == 0) ? W0 : ((z == 1) ? W1 : W2)) : W0;

  const f32x4 fz = {0.f, 0.f, 0.f, 0.f};
  f32x4 acc[4][4];
  #pragma unroll
  for (int a = 0; a < 4; ++a)
    #pragma unroll
    for (int b = 0; b < 4; ++b)
      acc[a][b] = fz;

  // stage K-tile t (128x32 A + 128x32 B): 4 gloads/thread (2 A + 2 B)
  auto STAGE = [&](int buf, int t) {
    const int k0 = t * 32;
    #pragma unroll
    for (int it = 0; it < 2; ++it) {
      int c = it*4 + w;                    // wave-uniform chunk 0..7
      int off16 = c*64 + lane;             // 16B-slot 0..511
      int r = off16 >> 2, p = off16 & 3;   // row 0..127, phys slot 0..3
      int s = p ^ ((r >> 1) & 3);          // PMC-proven conflict-free swizzle
      gload_lds16(A  + (size_t)(m0 + r)*DMODEL + k0 + s*8, (char*)sA[buf] + c*1024);
      gload_lds16(Bw + (size_t)(n0 + r)*DMODEL + k0 + s*8, (char*)sB[buf] + c*1024);
    }
  };

  const int NT = DMODEL / 32;   // 32 K-tiles
  STAGE(0, 0);
  STAGE(1, 1);                  // 8 VMEM ops outstanding

  for (int t = 0; t < NT; ++t) {
    const int cur = t % 3;
    // tile t landed (t+1's 4 loads may stay in flight); tail drains fully
    if (t >= NT - 1) asm volatile("s_waitcnt vmcnt(0)" ::: "memory");
    else             asm volatile("s_waitcnt vmcnt(4)" ::: "memory");
    __builtin_amdgcn_s_barrier();          // all waves' tile-t loads landed AND
                                           // all waves done reading buf[(t-1)%3]
    __builtin_amdgcn_sched_barrier(0);
    if (t + 2 < NT) STAGE((t + 2) % 3, t + 2);   // refill freed buffer
    __builtin_amdgcn_sched_barrier(0);

    bf16x8 af[4], bfr[4];
    #pragma unroll
    for (int mi = 0; mi < 4; ++mi) {
      int rr = wm*64 + mi*16 + li;
      int sp = lg ^ ((rr >> 1) & 3);
      af[mi] = *(const bf16x8*)((const char*)sA[cur] + rr*64 + sp*16);
    }
    #pragma unroll
    for (int ni = 0; ni < 4; ++ni) {
      int rr = wn*64 + ni*16 + li;
      int sp = lg ^ ((rr >> 1) & 3);
      bfr[ni] = *(const bf16x8*)((const char*)sB[cur] + rr*64 + sp*16);
    }
    __builtin_amdgcn_s_setprio(1);
    #pragma unroll
    for (int mi = 0; mi < 4; ++mi)
      #pragma unroll
      for (int ni = 0; ni < 4; ++ni)
        acc[mi][ni] = mfma16(af[mi], bfr[ni], acc[mi][ni]);
    __builtin_amdgcn_s_setprio(0);
    __builtin_amdgcn_sched_barrier(0);     // keep this tile's reads above
                                           // the next iteration's barrier
  }

  unsigned short* Odst = O0;
  if (EPI == 0) Odst = (z == 0) ? O0 : ((z == 1) ? O1 : O2);

  float invf[4];
  if (EPI == 0) {
    #pragma unroll
    for (int ni = 0; ni < 4; ++ni) {
      int i_of = (ni*16 + li) >> 1;
      invf[ni] = exp2f(-0.41524101186092029f * (float)i_of);
    }
  }

  #pragma unroll
  for (int mi = 0; mi < 4; ++mi) {
    #pragma unroll
    for (int ni = 0; ni < 4; ++ni) {
      #pragma unroll
      for (int r = 0; r < 4; ++r) {
        int m = m0 + wm*64 + mi*16 + lg*4 + r;   // D row = (lane>>4)*4 + reg
        int n = n0 + wn*64 + ni*16 + li;         // D col = lane&15
        float v = acc[mi][ni][r];
        if (EPI == 0) {
          int b = m >> 11, sq = m & (SEQ-1), hh = n >> 6, dk = n & 63;
          float prt = __shfl_xor(v, 1);          // RoPE pair (adjacent lanes)
          if (z == 2) {
            Odst[(((size_t)b*NHEADS + hh)*DKH + dk)*SEQ + sq] = f2bf(v);   // V^T
          } else {
            float ang = (float)sq * invf[ni];
            float sn, cs;
            __sincosf(ang, &sn, &cs);
            float out = (li & 1) ? (sn*prt + cs*v) : (cs*v - sn*prt);
            if (z == 0) out *= 0.18033688011112043f;   // (1/8) * log2(e)
            Odst[(((size_t)b*NHEADS + hh)*SEQ + sq)*DKH + dk] = f2bf(out);
          }
        } else {
          Of[(size_t)m*DMODEL + n] = v;
        }
      }
    }
  }
}

// ---------------- causal flash attention (frozen round-14) ----------------
__global__ __launch_bounds__(512)
void attn_kernel(const unsigned short* __restrict__ Qg,
                 const unsigned short* __restrict__ Kg,
                 const unsigned short* __restrict__ Vtg,
                 unsigned short* __restrict__ Og)
{
  const int lgid = (blockIdx.x & 7) * 64 + (blockIdx.x >> 3);
  const int px = lgid & 7;
  const int bh = lgid >> 3;
  const int tid = threadIdx.x;
  const int lane = tid & 63, w = tid >> 6;
  const int li = lane & 15, lg = lane >> 4;
  const float THRL2 = 11.0f;

  __shared__ unsigned short sK[2][64*64];
  __shared__ unsigned short sV[2][64*64];
  __shared__ unsigned short sP[8][16*72];
  unsigned short* sPw = sP[w];

  const size_t bhBase = (size_t)bh * SEQ * DKH;

  bf16x8 onesf;
  {
    __bf16 ob = (__bf16)1.0f;
    #pragma unroll
    for (int j = 0; j < 8; ++j) onesf[j] = ob;
  }
  const f32x4 fz = {0.f, 0.f, 0.f, 0.f};

  auto STAGE = [&](int buf, int t) {
    const int kv0 = t * 64;
    int off16 = w*64 + lane;
    int r = off16 >> 3, p = off16 & 7;
    int s = p ^ (r & 7);
    gload_lds16(Kg  + bhBase + (size_t)(kv0 + r)*DKH + s*8, (char*)sK[buf] + w*1024);
    gload_lds16(Vtg + bhBase + (size_t)r*SEQ + kv0 + s*8,   (char*)sV[buf] + w*1024);
  };

  #pragma unroll 1
  for (int pass = 0; pass < 2; ++pass) {
    const int qt = pass ? (15 - px) : px;
    const int q0 = qt * 128;
    const int myrow0 = q0 + w*16;

    bf16x8 qf[2];
    {
      const unsigned short* qp = Qg + bhBase + (size_t)(myrow0 + li)*DKH + lg*8;
      qf[0] = *(const bf16x8*)qp;
      qf[1] = *(const bf16x8*)(qp + 32);
    }

    f32x4 acc_o[4], ls4;
    float m_r[4];
    #pragma unroll
    for (int nt = 0; nt < 4; ++nt) acc_o[nt] = fz;
    ls4 = fz;
    #pragma unroll
    for (int kr = 0; kr < 4; ++kr) m_r[kr] = -1e30f;

    const int nt_stage = 2*qt + 2;
    const int last_t  = 2*qt + (w >= 4 ? 1 : 0);

    STAGE(0, 0);
    STAGE(1, 1);

    for (int t = 0; t < nt_stage; ++t) {
      const int cur = t & 1;
      if (t == nt_stage - 1) asm volatile("s_waitcnt vmcnt(0)" ::: "memory");
      else                   asm volatile("s_waitcnt vmcnt(2)" ::: "memory");
      __builtin_amdgcn_s_barrier();
      __builtin_amdgcn_sched_barrier(0);

      if (t <= last_t) {
        const int kv0 = t * 64;
        f32x4 sc[4];
        #pragma unroll
        for (int nt = 0; nt < 4; ++nt) sc[nt] = fz;
        __builtin_amdgcn_s_setprio(1);
        #pragma unroll
        for (int kf = 0; kf < 2; ++kf) {
          #pragma unroll
          for (int nt = 0; nt < 4; ++nt) {
            int row = nt*16 + li;
            int sp = (kf*4 + lg) ^ (row & 7);
            bf16x8 kb = *(const bf16x8*)(sK[cur] + row*64 + sp*8);
            sc[nt] = mfma16(qf[kf], kb, sc[nt]);
          }
        }
        __builtin_amdgcn_s_setprio(0);

        if (t == last_t) {
          #pragma unroll
          for (int nt = 0; nt < 4; ++nt)
            #pragma unroll
            for (int kr = 0; kr < 4; ++kr) {
              int col = kv0 + nt*16 + li;
              int row = myrow0 + lg*4 + kr;
              if (col > row) sc[nt][kr] = -1e30f;
            }
        }

        // T13 lazy max: per-lane max test; tree+rescale only when exceeded
        float pm[4];
        #pragma unroll
        for (int kr = 0; kr < 4; ++kr)
          pm[kr] = fmaxf(fmaxf(sc[0][kr], sc[1][kr]), fmaxf(sc[2][kr], sc[3][kr]));
        int need = (pm[0] > m_r[0] + THRL2) | (pm[1] > m_r[1] + THRL2) |
                   (pm[2] > m_r[2] + THRL2) | (pm[3] > m_r[3] + THRL2);
        if (__any(need)) {
          #pragma unroll
          for (int kr = 0; kr < 4; ++kr) {
            float m2 = pm[kr];
            m2 = fmaxf(m2, __shfl_xor(m2, 1));
            m2 = fmaxf(m2, __shfl_xor(m2, 2));
            m2 = fmaxf(m2, __shfl_xor(m2, 4));
            m2 = fmaxf(m2, __shfl_xor(m2, 8));
            float mn = fmaxf(m_r[kr], m2);
            float scl = __builtin_amdgcn_exp2f(m_r[kr] - mn);
            m_r[kr] = mn;
            #pragma unroll
            for (int nt = 0; nt < 4; ++nt) acc_o[nt][kr] *= scl;
            ls4[kr] *= scl;
          }
        }
        #pragma unroll
        for (int nt = 0; nt < 4; ++nt)
          #pragma unroll
          for (int kr = 0; kr < 4; ++kr)
            sc[nt][kr] = __builtin_amdgcn_exp2f(sc[nt][kr] - m_r[kr]);

        #pragma unroll
        for (int nt = 0; nt < 4; ++nt)
          #pragma unroll
          for (int kr = 0; kr < 4; ++kr)
            sPw[(lg*4 + kr)*72 + nt*16 + li] = f2bf(sc[nt][kr]);

        bf16x8 pa[2];
        #pragma unroll
        for (int kf = 0; kf < 2; ++kf)
          pa[kf] = *(const bf16x8*)(sPw + li*72 + kf*32 + lg*8);

        __builtin_amdgcn_s_setprio(1);
        ls4 = mfma16(pa[0], onesf, ls4);
        ls4 = mfma16(pa[1], onesf, ls4);
        #pragma unroll
        for (int kf = 0; kf < 2; ++kf)
          #pragma unroll
          for (int nt = 0; nt < 4; ++nt) {
            int rr = nt*16 + li;
            int sp = (kf*4 + lg) ^ (rr & 7);
            bf16x8 vb = *(const bf16x8*)(sV[cur] + rr*64 + sp*8);
            acc_o[nt] = mfma16(pa[kf], vb, acc_o[nt]);
          }
        __builtin_amdgcn_s_setprio(0);
      }

      __builtin_amdgcn_sched_barrier(0);
      __builtin_amdgcn_s_barrier();
      __builtin_amdgcn_sched_barrier(0);
      if (t + 2 < nt_stage) STAGE(cur, t + 2);
    }

    const int b = bh >> 4, hh = bh & 15;
    #pragma unroll
    for (int kr = 0; kr < 4; ++kr) {
      float inv = __builtin_amdgcn_rcpf(ls4[kr]);
      int srow = myrow0 + lg*4 + kr;
      size_t orow = ((size_t)b*SEQ + srow)*DMODEL + (size_t)hh*DKH;
      #pragma unroll
      for (int nt = 0; nt < 4; ++nt)
        Og[orow + nt*16 + li] = f2bf(acc_o[nt][kr] * inv);
    }
  }
}

extern "C" void kernel_launch(void* const* d_in, const int* in_sizes, int n_in,
                              void* d_out, int out_size, void* d_ws, size_t ws_size,
                              hipStream_t stream)
{
  (void)in_sizes; (void)n_in; (void)out_size; (void)ws_size;
  const float* X  = (const float*)d_in[0];
  const float* Wq = (const float*)d_in[1];
  const float* Wk = (const float*)d_in[2];
  const float* Wv = (const float*)d_in[3];
  const float* Wo = (const float*)d_in[4];

  // d_ws budget: 40 MiB. Q/K bf16 scratch (32 MiB) lives inside d_out (33.5 MiB),
  // dead until the final out-projection overwrites it (stream-ordered).
  char* ws = (char*)d_ws;
  const size_t SZ_X = (size_t)8192 * 1024 * 2;   // 16 MiB (bf16)
  const size_t SZ_W = (size_t)1024 * 1024 * 2;   // 2 MiB  (bf16)
  unsigned short* Xb  = (unsigned short*)(ws);
  unsigned short* Wqb = (unsigned short*)(ws + SZ_X);
  unsigned short* Wkb = (unsigned short*)(ws + SZ_X + 1*SZ_W);
  unsigned short* Wvb = (unsigned short*)(ws + SZ_X + 2*SZ_W);
  unsigned short* Wob = (unsigned short*)(ws + SZ_X + 3*SZ_W);
  unsigned short* Vtb = (unsigned short*)(ws + SZ_X + 4*SZ_W);   // V^T, ..40 MiB
  unsigned short* Qb  = (unsigned short*)d_out;                  // 16 MiB scratch
  unsigned short* Kb  = Qb + (size_t)8192 * 1024;                // 16 MiB scratch
  unsigned short* Ob  = Xb;   // X dead after QKV projection

  cast_kernel<<<8192, 256, 0, stream>>>(X, Xb, 8388608/4);
  cast4_kernel<<<dim3(1024, 4), 256, 0, stream>>>(Wq, Wk, Wv, Wo,
                                                  Wqb, Wkb, Wvb, Wob, 1048576/4);

  gemm_bt<0><<<1536, 256, 0, stream>>>(Xb, Wqb, Wkb, Wvb, Qb, Kb, Vtb, nullptr);
  attn_kernel<<<512, 512, 0, stream>>>(Qb, Kb, Vtb, Ob);
  gemm_bt<1><<<512, 256, 0, stream>>>(Ob, Wob, nullptr, nullptr,
                                      nullptr, nullptr, nullptr,
                                      (float*)d_out);
}

// Round 16
// 169.585 us; speedup vs baseline: 1.1805x; 1.1805x over previous
//
#include <hip/hip_runtime.h>

#define SEQ     2048
#define DMODEL  1024
#define NHEADS  16
#define DKH     64
#define BATCH   4

typedef __bf16 bf16x8 __attribute__((ext_vector_type(8)));
typedef float  f32x4  __attribute__((ext_vector_type(4)));
typedef float  f32x16 __attribute__((ext_vector_type(16)));

static __device__ __forceinline__ unsigned short f2bf(float x) {
  unsigned int u = __float_as_uint(x);
  u += 0x7fffu + ((u >> 16) & 1u);
  return (unsigned short)(u >> 16);
}
static __device__ __forceinline__ float bf2f(unsigned short b) {
  return __uint_as_float(((unsigned int)b) << 16);
}
static __device__ __forceinline__ void gload_lds16(const void* g, void* lds) {
  __builtin_amdgcn_global_load_lds((const __attribute__((address_space(1))) void*)g,
                                   (__attribute__((address_space(3))) void*)lds,
                                   16, 0, 0);
}
static __device__ __forceinline__ f32x4 mfma16(bf16x8 a, bf16x8 b, f32x4 c) {
  return __builtin_amdgcn_mfma_f32_16x16x32_bf16(a, b, c, 0, 0, 0);
}
static __device__ __forceinline__ f32x16 mfma32(bf16x8 a, bf16x8 b, f32x16 c) {
  return __builtin_amdgcn_mfma_f32_32x32x16_bf16(a, b, c, 0, 0, 0);
}

// ---------------- fp32 -> bf16 cast ----------------
__global__ void cast_kernel(const float* __restrict__ src,
                            unsigned short* __restrict__ dst, int n4) {
  int i = blockIdx.x * 256 + threadIdx.x;
  if (i >= n4) return;
  float4 v = ((const float4*)src)[i];
  ushort4 o;
  o.x = f2bf(v.x); o.y = f2bf(v.y); o.z = f2bf(v.z); o.w = f2bf(v.w);
  ((ushort4*)dst)[i] = o;
}

// 4 weight matrices in one launch (blockIdx.y selects)
__global__ void cast4_kernel(const float* __restrict__ s0, const float* __restrict__ s1,
                             const float* __restrict__ s2, const float* __restrict__ s3,
                             unsigned short* __restrict__ d0, unsigned short* __restrict__ d1,
                             unsigned short* __restrict__ d2, unsigned short* __restrict__ d3,
                             int n4) {
  int i = blockIdx.x * 256 + threadIdx.x;
  if (i >= n4) return;
  const float* s = (blockIdx.y == 0) ? s0 : (blockIdx.y == 1) ? s1 : (blockIdx.y == 2) ? s2 : s3;
  unsigned short* d = (blockIdx.y == 0) ? d0 : (blockIdx.y == 1) ? d1 : (blockIdx.y == 2) ? d2 : d3;
  float4 v = ((const float4*)s)[i];
  ushort4 o;
  o.x = f2bf(v.x); o.y = f2bf(v.y); o.z = f2bf(v.z); o.w = f2bf(v.w);
  ((ushort4*)d)[i] = o;
}

// ---------------- GEMM: C = A (8192x1024) * W^T, W is [out][in] ----------------
// Round-14-proven outer structure: 128x128 tile, 4 waves, BK=64, dbuf,
// counted vmcnt(8), raw barriers. NEW: inner compute uses 32x32x16 MFMA
// (same ds_read count/bytes, HALF the MFMA instructions); V^T epilogue goes
// through an LDS transpose for coalesced 16B stores (was a 2B/4KB scatter).
// EPI 0: RoPE fused into Q/K epilogue (Q scaled by log2e/8); V (z==2) -> V^T.
// EPI 1: fp32 [m][1024].
template<int EPI>
__global__ __launch_bounds__(256)
void gemm_bt(const unsigned short* __restrict__ A,
             const unsigned short* __restrict__ W0,
             const unsigned short* __restrict__ W1,
             const unsigned short* __restrict__ W2,
             unsigned short* __restrict__ O0,
             unsigned short* __restrict__ O1,
             unsigned short* __restrict__ O2,
             float* __restrict__ Of)
{
  __shared__ unsigned short smem[4][128*64];   // [0..1]=A dbuf, [2..3]=B dbuf (64 KiB)
  const int tid = threadIdx.x;
  const int lane = tid & 63, w = tid >> 6;
  const int wm = w >> 1, wn = w & 1;
  const int l31 = lane & 31, lg2 = lane >> 5;

  const int NWG = (EPI == 0) ? 1536 : 512;
  const int CPX = NWG / 8;
  const int lgid = (blockIdx.x & 7) * CPX + (blockIdx.x >> 3);
  const int n0 = (lgid & 7) * 128;
  const int m0 = ((lgid >> 3) & 63) * 128;
  const int z  = (EPI == 0) ? (lgid >> 9) : 0;
  const unsigned short* Bw = (EPI == 0)
      ? ((z == 0) ? W0 : ((z == 1) ? W1 : W2)) : W0;

  f32x16 acc[2][2];
  #pragma unroll
  for (int a = 0; a < 2; ++a)
    #pragma unroll
    for (int b = 0; b < 2; ++b)
      #pragma unroll
      for (int r = 0; r < 16; ++r)
        acc[a][b][r] = 0.f;

  auto STAGE = [&](int buf, int t) {
    const int k0 = t * 64;
    #pragma unroll
    for (int it = 0; it < 4; ++it) {
      int c = it*4 + w;
      int off16 = c*64 + lane;
      int r = off16 >> 3, p = off16 & 7;
      int s = p ^ (r & 7);
      gload_lds16(A  + (size_t)(m0 + r)*DMODEL + k0 + s*8, (char*)smem[buf]     + c*1024);
      gload_lds16(Bw + (size_t)(n0 + r)*DMODEL + k0 + s*8, (char*)smem[2 + buf] + c*1024);
    }
  };

  const int NT = DMODEL / 64;
  STAGE(0, 0);
  STAGE(1, 1);

  for (int t = 0; t < NT; ++t) {
    const int cur = t & 1;
    if (t == NT - 1) asm volatile("s_waitcnt vmcnt(0)" ::: "memory");
    else             asm volatile("s_waitcnt vmcnt(8)" ::: "memory");
    __builtin_amdgcn_s_barrier();
    __builtin_amdgcn_sched_barrier(0);

    #pragma unroll
    for (int ks = 0; ks < 4; ++ks) {       // K-slices of 16 within BK=64
      bf16x8 af[2], bg[2];
      #pragma unroll
      for (int bi = 0; bi < 2; ++bi) {
        int row = wm*64 + bi*32 + l31;
        int sp = (ks*2 + lg2) ^ (row & 7);
        af[bi] = *(const bf16x8*)((const char*)smem[cur] + row*128 + sp*16);
      }
      #pragma unroll
      for (int bj = 0; bj < 2; ++bj) {
        int row = wn*64 + bj*32 + l31;
        int sp = (ks*2 + lg2) ^ (row & 7);
        bg[bj] = *(const bf16x8*)((const char*)smem[2 + cur] + row*128 + sp*16);
      }
      __builtin_amdgcn_s_setprio(1);
      #pragma unroll
      for (int bi = 0; bi < 2; ++bi)
        #pragma unroll
        for (int bj = 0; bj < 2; ++bj)
          acc[bi][bj] = mfma32(af[bi], bg[bj], acc[bi][bj]);
      __builtin_amdgcn_s_setprio(0);
    }

    __builtin_amdgcn_sched_barrier(0);
    __builtin_amdgcn_s_barrier();
    __builtin_amdgcn_sched_barrier(0);
    if (t + 2 < NT) STAGE(cur, t + 2);
  }

  // C/D layout (m74/m101-verified): col = lane&31, row = (r&3)+8*(r>>2)+4*(lane>>5)
  if (EPI == 1) {
    #pragma unroll
    for (int bi = 0; bi < 2; ++bi)
      #pragma unroll
      for (int bj = 0; bj < 2; ++bj)
        #pragma unroll
        for (int r = 0; r < 16; ++r) {
          int m = m0 + wm*64 + bi*32 + (r & 3) + 8*(r >> 2) + 4*lg2;
          int n = n0 + wn*64 + bj*32 + l31;
          Of[(size_t)m*DMODEL + n] = acc[bi][bj][r];
        }
    return;
  }

  unsigned short* Odst = (z == 0) ? O0 : ((z == 1) ? O1 : O2);

  if (z == 2) {
    // V^T: acc -> LDS [n][m] (136-short padded rows), then coalesced stores
    unsigned short* tb = (unsigned short*)smem;          // 128 x 136 (34.8 KiB)
    #pragma unroll
    for (int bi = 0; bi < 2; ++bi)
      #pragma unroll
      for (int bj = 0; bj < 2; ++bj) {
        int n_loc = wn*64 + bj*32 + l31;
        #pragma unroll
        for (int g = 0; g < 4; ++g) {
          int m_loc = wm*64 + bi*32 + 8*g + 4*lg2;
          ushort4 pk;
          pk.x = f2bf(acc[bi][bj][g*4 + 0]);
          pk.y = f2bf(acc[bi][bj][g*4 + 1]);
          pk.z = f2bf(acc[bi][bj][g*4 + 2]);
          pk.w = f2bf(acc[bi][bj][g*4 + 3]);
          *(ushort4*)(tb + n_loc*136 + m_loc) = pk;      // 8B aligned
        }
      }
    __syncthreads();
    const int bb  = m0 >> 11;
    const int sq0 = m0 & (SEQ - 1);
    const size_t obase = (size_t)bb * NHEADS * DKH * SEQ;
    #pragma unroll
    for (int it = 0; it < 8; ++it) {
      int nn = it*16 + (tid >> 4);                       // 0..127
      int cc = tid & 15;                                 // 16B chunk in m
      bf16x8 v8 = *(const bf16x8*)(tb + nn*136 + cc*8);  // 16B aligned (272|16)
      int hh = (n0 + nn) >> 6;
      int dk = nn & 63;
      *(bf16x8*)&Odst[obase + ((size_t)hh*DKH + dk)*SEQ + sq0 + cc*8] = v8;
    }
  } else {
    float invf2[2];
    #pragma unroll
    for (int bj = 0; bj < 2; ++bj)
      invf2[bj] = exp2f(-0.41524101186092029f * (float)((bj*32 + l31) >> 1));
    #pragma unroll
    for (int bi = 0; bi < 2; ++bi)
      #pragma unroll
      for (int bj = 0; bj < 2; ++bj)
        #pragma unroll
        for (int r = 0; r < 16; ++r) {
          int m = m0 + wm*64 + bi*32 + (r & 3) + 8*(r >> 2) + 4*lg2;
          int n = n0 + wn*64 + bj*32 + l31;
          float v = acc[bi][bj][r];
          int b = m >> 11, sq = m & (SEQ-1), hh = n >> 6, dk = n & 63;
          float prt = __shfl_xor(v, 1);                  // RoPE pair (adjacent lanes)
          float ang = (float)sq * invf2[bj];
          float sn, cs;
          __sincosf(ang, &sn, &cs);
          float out = (l31 & 1) ? (sn*prt + cs*v) : (cs*v - sn*prt);
          if (z == 0) out *= 0.18033688011112043f;       // (1/8) * log2(e)
          Odst[(((size_t)b*NHEADS + hh)*SEQ + sq)*DKH + dk] = f2bf(out);
        }
  }
}

// ---------------- causal flash attention (frozen round-14) ----------------
__global__ __launch_bounds__(512)
void attn_kernel(const unsigned short* __restrict__ Qg,
                 const unsigned short* __restrict__ Kg,
                 const unsigned short* __restrict__ Vtg,
                 unsigned short* __restrict__ Og)
{
  const int lgid = (blockIdx.x & 7) * 64 + (blockIdx.x >> 3);
  const int px = lgid & 7;
  const int bh = lgid >> 3;
  const int tid = threadIdx.x;
  const int lane = tid & 63, w = tid >> 6;
  const int li = lane & 15, lg = lane >> 4;
  const float THRL2 = 11.0f;

  __shared__ unsigned short sK[2][64*64];
  __shared__ unsigned short sV[2][64*64];
  __shared__ unsigned short sP[8][16*72];
  unsigned short* sPw = sP[w];

  const size_t bhBase = (size_t)bh * SEQ * DKH;

  bf16x8 onesf;
  {
    __bf16 ob = (__bf16)1.0f;
    #pragma unroll
    for (int j = 0; j < 8; ++j) onesf[j] = ob;
  }
  const f32x4 fz = {0.f, 0.f, 0.f, 0.f};

  auto STAGE = [&](int buf, int t) {
    const int kv0 = t * 64;
    int off16 = w*64 + lane;
    int r = off16 >> 3, p = off16 & 7;
    int s = p ^ (r & 7);
    gload_lds16(Kg  + bhBase + (size_t)(kv0 + r)*DKH + s*8, (char*)sK[buf] + w*1024);
    gload_lds16(Vtg + bhBase + (size_t)r*SEQ + kv0 + s*8,   (char*)sV[buf] + w*1024);
  };

  #pragma unroll 1
  for (int pass = 0; pass < 2; ++pass) {
    const int qt = pass ? (15 - px) : px;
    const int q0 = qt * 128;
    const int myrow0 = q0 + w*16;

    bf16x8 qf[2];
    {
      const unsigned short* qp = Qg + bhBase + (size_t)(myrow0 + li)*DKH + lg*8;
      qf[0] = *(const bf16x8*)qp;
      qf[1] = *(const bf16x8*)(qp + 32);
    }

    f32x4 acc_o[4], ls4;
    float m_r[4];
    #pragma unroll
    for (int nt = 0; nt < 4; ++nt) acc_o[nt] = fz;
    ls4 = fz;
    #pragma unroll
    for (int kr = 0; kr < 4; ++kr) m_r[kr] = -1e30f;

    const int nt_stage = 2*qt + 2;
    const int last_t  = 2*qt + (w >= 4 ? 1 : 0);

    STAGE(0, 0);
    STAGE(1, 1);

    for (int t = 0; t < nt_stage; ++t) {
      const int cur = t & 1;
      if (t == nt_stage - 1) asm volatile("s_waitcnt vmcnt(0)" ::: "memory");
      else                   asm volatile("s_waitcnt vmcnt(2)" ::: "memory");
      __builtin_amdgcn_s_barrier();
      __builtin_amdgcn_sched_barrier(0);

      if (t <= last_t) {
        const int kv0 = t * 64;
        f32x4 sc[4];
        #pragma unroll
        for (int nt = 0; nt < 4; ++nt) sc[nt] = fz;
        __builtin_amdgcn_s_setprio(1);
        #pragma unroll
        for (int kf = 0; kf < 2; ++kf) {
          #pragma unroll
          for (int nt = 0; nt < 4; ++nt) {
            int row = nt*16 + li;
            int sp = (kf*4 + lg) ^ (row & 7);
            bf16x8 kb = *(const bf16x8*)(sK[cur] + row*64 + sp*8);
            sc[nt] = mfma16(qf[kf], kb, sc[nt]);
          }
        }
        __builtin_amdgcn_s_setprio(0);

        if (t == last_t) {
          #pragma unroll
          for (int nt = 0; nt < 4; ++nt)
            #pragma unroll
            for (int kr = 0; kr < 4; ++kr) {
              int col = kv0 + nt*16 + li;
              int row = myrow0 + lg*4 + kr;
              if (col > row) sc[nt][kr] = -1e30f;
            }
        }

        // T13 lazy max: per-lane max test; tree+rescale only when exceeded
        float pm[4];
        #pragma unroll
        for (int kr = 0; kr < 4; ++kr)
          pm[kr] = fmaxf(fmaxf(sc[0][kr], sc[1][kr]), fmaxf(sc[2][kr], sc[3][kr]));
        int need = (pm[0] > m_r[0] + THRL2) | (pm[1] > m_r[1] + THRL2) |
                   (pm[2] > m_r[2] + THRL2) | (pm[3] > m_r[3] + THRL2);
        if (__any(need)) {
          #pragma unroll
          for (int kr = 0; kr < 4; ++kr) {
            float m2 = pm[kr];
            m2 = fmaxf(m2, __shfl_xor(m2, 1));
            m2 = fmaxf(m2, __shfl_xor(m2, 2));
            m2 = fmaxf(m2, __shfl_xor(m2, 4));
            m2 = fmaxf(m2, __shfl_xor(m2, 8));
            float mn = fmaxf(m_r[kr], m2);
            float scl = __builtin_amdgcn_exp2f(m_r[kr] - mn);
            m_r[kr] = mn;
            #pragma unroll
            for (int nt = 0; nt < 4; ++nt) acc_o[nt][kr] *= scl;
            ls4[kr] *= scl;
          }
        }
        #pragma unroll
        for (int nt = 0; nt < 4; ++nt)
          #pragma unroll
          for (int kr = 0; kr < 4; ++kr)
            sc[nt][kr] = __builtin_amdgcn_exp2f(sc[nt][kr] - m_r[kr]);

        #pragma unroll
        for (int nt = 0; nt < 4; ++nt)
          #pragma unroll
          for (int kr = 0; kr < 4; ++kr)
            sPw[(lg*4 + kr)*72 + nt*16 + li] = f2bf(sc[nt][kr]);

        bf16x8 pa[2];
        #pragma unroll
        for (int kf = 0; kf < 2; ++kf)
          pa[kf] = *(const bf16x8*)(sPw + li*72 + kf*32 + lg*8);

        __builtin_amdgcn_s_setprio(1);
        ls4 = mfma16(pa[0], onesf, ls4);
        ls4 = mfma16(pa[1], onesf, ls4);
        #pragma unroll
        for (int kf = 0; kf < 2; ++kf)
          #pragma unroll
          for (int nt = 0; nt < 4; ++nt) {
            int rr = nt*16 + li;
            int sp = (kf*4 + lg) ^ (rr & 7);
            bf16x8 vb = *(const bf16x8*)(sV[cur] + rr*64 + sp*8);
            acc_o[nt] = mfma16(pa[kf], vb, acc_o[nt]);
          }
        __builtin_amdgcn_s_setprio(0);
      }

      __builtin_amdgcn_sched_barrier(0);
      __builtin_amdgcn_s_barrier();
      __builtin_amdgcn_sched_barrier(0);
      if (t + 2 < nt_stage) STAGE(cur, t + 2);
    }

    const int b = bh >> 4, hh = bh & 15;
    #pragma unroll
    for (int kr = 0; kr < 4; ++kr) {
      float inv = __builtin_amdgcn_rcpf(ls4[kr]);
      int srow = myrow0 + lg*4 + kr;
      size_t orow = ((size_t)b*SEQ + srow)*DMODEL + (size_t)hh*DKH;
      #pragma unroll
      for (int nt = 0; nt < 4; ++nt)
        Og[orow + nt*16 + li] = f2bf(acc_o[nt][kr] * inv);
    }
  }
}

extern "C" void kernel_launch(void* const* d_in, const int* in_sizes, int n_in,
                              void* d_out, int out_size, void* d_ws, size_t ws_size,
                              hipStream_t stream)
{
  (void)in_sizes; (void)n_in; (void)out_size; (void)ws_size;
  const float* X  = (const float*)d_in[0];
  const float* Wq = (const float*)d_in[1];
  const float* Wk = (const float*)d_in[2];
  const float* Wv = (const float*)d_in[3];
  const float* Wo = (const float*)d_in[4];

  // d_ws budget: 40 MiB. Q/K bf16 scratch (32 MiB) lives inside d_out (33.5 MiB),
  // dead until the final out-projection overwrites it (stream-ordered).
  char* ws = (char*)d_ws;
  const size_t SZ_X = (size_t)8192 * 1024 * 2;   // 16 MiB (bf16)
  const size_t SZ_W = (size_t)1024 * 1024 * 2;   // 2 MiB  (bf16)
  unsigned short* Xb  = (unsigned short*)(ws);
  unsigned short* Wqb = (unsigned short*)(ws + SZ_X);
  unsigned short* Wkb = (unsigned short*)(ws + SZ_X + 1*SZ_W);
  unsigned short* Wvb = (unsigned short*)(ws + SZ_X + 2*SZ_W);
  unsigned short* Wob = (unsigned short*)(ws + SZ_X + 3*SZ_W);
  unsigned short* Vtb = (unsigned short*)(ws + SZ_X + 4*SZ_W);   // V^T, ..40 MiB
  unsigned short* Qb  = (unsigned short*)d_out;                  // 16 MiB scratch
  unsigned short* Kb  = Qb + (size_t)8192 * 1024;                // 16 MiB scratch
  unsigned short* Ob  = Xb;   // X dead after QKV projection

  cast_kernel<<<8192, 256, 0, stream>>>(X, Xb, 8388608/4);
  cast4_kernel<<<dim3(1024, 4), 256, 0, stream>>>(Wq, Wk, Wv, Wo,
                                                  Wqb, Wkb, Wvb, Wob, 1048576/4);

  gemm_bt<0><<<1536, 256, 0, stream>>>(Xb, Wqb, Wkb, Wvb, Qb, Kb, Vtb, nullptr);
  attn_kernel<<<512, 512, 0, stream>>>(Qb, Kb, Vtb, Ob);
  gemm_bt<1><<<512, 256, 0, stream>>>(Ob, Wob, nullptr, nullptr,
                                      nullptr, nullptr, nullptr,
                                      (float*)d_out);
}